// Round 1
// baseline (467.320 us; speedup 1.0000x reference)
//
#include <hip/hip_runtime.h>

// Problem constants
#define B_TOK 32768
#define D_IN  256
#define H1D   512
#define H2D   256
#define NE    16
#define NO    64

typedef _Float16 half8 __attribute__((ext_vector_type(8)));
typedef _Float16 half4 __attribute__((ext_vector_type(4)));
typedef float   float4_t __attribute__((ext_vector_type(4)));

// ---------------------------------------------------------------------------
// gates = softmax(x @ gate_w + gate_b)   [B, E] fp32
// one thread per token; gate_w staged in LDS
// ---------------------------------------------------------------------------
__global__ void gates_kernel(const float* __restrict__ x,
                             const float* __restrict__ gw,
                             const float* __restrict__ gb,
                             float* __restrict__ gates) {
  __shared__ float gwl[D_IN * NE];
  for (int i = threadIdx.x; i < D_IN * NE; i += 256) gwl[i] = gw[i];
  __syncthreads();
  int t = blockIdx.x * 256 + threadIdx.x;
  float lg[NE];
  #pragma unroll
  for (int e = 0; e < NE; ++e) lg[e] = gb[e];
  const float* xr = x + (size_t)t * D_IN;
  for (int d = 0; d < D_IN; ++d) {
    float xv = xr[d];
    #pragma unroll
    for (int e = 0; e < NE; ++e) lg[e] = fmaf(xv, gwl[d * NE + e], lg[e]);
  }
  float mx = lg[0];
  #pragma unroll
  for (int e = 1; e < NE; ++e) mx = fmaxf(mx, lg[e]);
  float s = 0.f;
  #pragma unroll
  for (int e = 0; e < NE; ++e) { lg[e] = __expf(lg[e] - mx); s += lg[e]; }
  float inv = 1.f / s;
  #pragma unroll
  for (int e = 0; e < NE; ++e) gates[(size_t)t * NE + e] = lg[e] * inv;
}

// ---------------------------------------------------------------------------
// Pack W1 [E][D][H1] fp32 -> B-fragment-linear fp16.
// Fragment (e, ntile 0..31, ktile 0..7): lane holds W1[e][kt*32+q*8+j][nt*16+l16]
// packed at ((e*32+nt)*8+kt)*512 + lane*8 halves (one coalesced 16B chunk/lane)
// ---------------------------------------------------------------------------
__global__ void pack_w1(const float* __restrict__ W1, _Float16* __restrict__ w1p) {
  int t = blockIdx.x * 256 + threadIdx.x;        // 16*32*8*64 = 262144 threads
  int lane = t & 63;
  int kt   = (t >> 6) & 7;
  int ntg  = (t >> 9) & 31;
  int e    = t >> 14;
  int n  = ntg * 16 + (lane & 15);
  int kb = kt * 32 + (lane >> 4) * 8;
  half8 v;
  #pragma unroll
  for (int j = 0; j < 8; ++j)
    v[j] = (_Float16)W1[((size_t)(e * D_IN + kb + j)) * H1D + n];
  *(half8*)(w1p + (size_t)t * 8) = v;
}

// Pack W2 [E][H1][H2] fp32 -> fragments: (e, ntile 0..15, ktile 0..15)
__global__ void pack_w2(const float* __restrict__ W2, _Float16* __restrict__ w2p) {
  int t = blockIdx.x * 256 + threadIdx.x;        // 16*16*16*64 = 262144 threads
  int lane = t & 63;
  int ktg  = (t >> 6) & 15;
  int ntg  = (t >> 10) & 15;
  int e    = t >> 14;
  int n  = ntg * 16 + (lane & 15);
  int kb = ktg * 32 + (lane >> 4) * 8;
  half8 v;
  #pragma unroll
  for (int j = 0; j < 8; ++j)
    v[j] = (_Float16)W2[((size_t)(e * H1D + kb + j)) * H2D + n];
  *(half8*)(w2p + (size_t)t * 8) = v;
}

// w3h[e][h2] = W3[e][h2][:] . head_w ;  c3[e] = b3[e][:] . head_w
__global__ void w3h_kernel(const float* __restrict__ W3, const float* __restrict__ b3,
                           const float* __restrict__ hw, float* __restrict__ w3h,
                           float* __restrict__ c3) {
  int t = blockIdx.x * 256 + threadIdx.x;
  if (t < NE * H2D) {
    int e = t >> 8, h = t & 255;
    float s = 0.f;
    #pragma unroll
    for (int o = 0; o < NO; ++o) s = fmaf(W3[((size_t)(e * H2D + h)) * NO + o], hw[o], s);
    w3h[t] = s;
  } else if (t < NE * H2D + NE) {
    int e = t - NE * H2D;
    float s = 0.f;
    #pragma unroll
    for (int o = 0; o < NO; ++o) s = fmaf(b3[e * NO + o], hw[o], s);
    c3[e] = s;
  }
}

// ---------------------------------------------------------------------------
// Fused main kernel: per block = 64 tokens, loop 16 experts:
//   h1 = relu(x @ W1[e] + b1[e])  (in 2 chunks of 256 cols, via LDS)
//   h2 = relu(h1 @ W2[e] + b2[e]) (accumulated in VGPRs)
//   yts += gates[.,e] * (h2 . w3h[e] + c3[e])
// 4 waves; wave w owns h2 cols [w*64, w*64+64).
// ---------------------------------------------------------------------------
#define XSTR 264   // 256 + 8 halves pad (16B); keeps ds_read_b128 2-way max

__global__ __launch_bounds__(256, 2) void moe_main(
    const float* __restrict__ x,
    const float* __restrict__ b1,
    const float* __restrict__ b2,
    const _Float16* __restrict__ w1p,
    const _Float16* __restrict__ w2p,
    const float* __restrict__ gates,
    const float* __restrict__ w3h,
    const float* __restrict__ c3,
    const float* __restrict__ head_b,
    float* __restrict__ out) {
  __shared__ _Float16 x_lds[64 * XSTR];
  __shared__ _Float16 h1_lds[64 * XSTR];
  __shared__ float g_lds[64 * NE];
  __shared__ float partials[4 * 64];
  __shared__ float fused[64];

  const int tid  = threadIdx.x;
  const int w    = tid >> 6;
  const int lane = tid & 63;
  const int q    = lane >> 4;
  const int l16  = lane & 15;
  const int m0   = blockIdx.x * 64;

  // stage x tile (64 x 256 fp32 -> fp16 LDS), coalesced float4 loads
  for (int i = tid; i < 64 * 64; i += 256) {
    int row = i >> 6;
    int c4  = (i & 63) * 4;
    const float4* p = (const float4*)(x + (size_t)(m0 + row) * D_IN + c4);
    float4 v = *p;
    half4 h = { (_Float16)v.x, (_Float16)v.y, (_Float16)v.z, (_Float16)v.w };
    *(half4*)(x_lds + row * XSTR + c4) = h;
  }
  for (int i = tid; i < 64 * NE; i += 256) g_lds[i] = gates[(size_t)m0 * NE + i];
  if (tid < 64) fused[tid] = 0.0f;
  __syncthreads();

  for (int e = 0; e < NE; ++e) {
    float4_t h2[4][4];
    #pragma unroll
    for (int mt = 0; mt < 4; ++mt)
      #pragma unroll
      for (int nt = 0; nt < 4; ++nt)
        h2[mt][nt] = (float4_t){0.f, 0.f, 0.f, 0.f};

    #pragma unroll
    for (int ch = 0; ch < 2; ++ch) {
      // ---- L1: compute h1 cols [ch*256, ch*256+256), wave w does 4 n-tiles ----
      float4_t a1[4][4];
      #pragma unroll
      for (int mt = 0; mt < 4; ++mt)
        #pragma unroll
        for (int nt = 0; nt < 4; ++nt)
          a1[mt][nt] = (float4_t){0.f, 0.f, 0.f, 0.f};

      #pragma unroll
      for (int kt = 0; kt < 8; ++kt) {
        half8 xa[4];
        #pragma unroll
        for (int mt = 0; mt < 4; ++mt)
          xa[mt] = *(const half8*)(x_lds + (mt * 16 + l16) * XSTR + kt * 32 + q * 8);
        #pragma unroll
        for (int nt = 0; nt < 4; ++nt) {
          int ntg = ch * 16 + w * 4 + nt;
          half8 bf = *(const half8*)(w1p + ((size_t)((e * 32 + ntg) * 8 + kt)) * 512 + lane * 8);
          #pragma unroll
          for (int mt = 0; mt < 4; ++mt)
            a1[mt][nt] = __builtin_amdgcn_mfma_f32_16x16x32_f16(xa[mt], bf, a1[mt][nt], 0, 0, 0);
        }
      }

      __syncthreads();  // all waves done READING h1_lds (previous chunk's L2)

      // bias + relu + store h1 chunk to LDS (local cols 0..255)
      #pragma unroll
      for (int nt = 0; nt < 4; ++nt) {
        int col = w * 64 + nt * 16 + l16;
        float bb = b1[e * H1D + ch * 256 + col];
        #pragma unroll
        for (int mt = 0; mt < 4; ++mt) {
          #pragma unroll
          for (int r = 0; r < 4; ++r) {
            float hv = fmaxf(a1[mt][nt][r] + bb, 0.f);
            h1_lds[(mt * 16 + q * 4 + r) * XSTR + col] = (_Float16)hv;
          }
        }
      }
      __syncthreads();  // h1 chunk visible

      // ---- L2 partial: h2 += h1_chunk @ W2[ch*256:+256, wave's 64 cols] ----
      #pragma unroll
      for (int kt = 0; kt < 8; ++kt) {
        half8 ha[4];
        #pragma unroll
        for (int mt = 0; mt < 4; ++mt)
          ha[mt] = *(const half8*)(h1_lds + (mt * 16 + l16) * XSTR + kt * 32 + q * 8);
        #pragma unroll
        for (int nt = 0; nt < 4; ++nt) {
          int ntg = w * 4 + nt;
          int ktg = ch * 8 + kt;
          half8 bf = *(const half8*)(w2p + ((size_t)((e * 16 + ntg) * 16 + ktg)) * 512 + lane * 8);
          #pragma unroll
          for (int mt = 0; mt < 4; ++mt)
            h2[mt][nt] = __builtin_amdgcn_mfma_f32_16x16x32_f16(ha[mt], bf, h2[mt][nt], 0, 0, 0);
        }
      }
    }

    // ---- epilogue: relu(h2+b2) . w3h, reduce, gate-weighted accumulate ----
    float b2v[4], w3v[4];
    #pragma unroll
    for (int nt = 0; nt < 4; ++nt) {
      int n = w * 64 + nt * 16 + l16;
      b2v[nt] = b2[e * H2D + n];
      w3v[nt] = w3h[e * H2D + n];
    }
    float s[4][4];  // [mt][r] row-partials over this lane's 4 columns
    #pragma unroll
    for (int mt = 0; mt < 4; ++mt)
      #pragma unroll
      for (int r = 0; r < 4; ++r) s[mt][r] = 0.f;
    #pragma unroll
    for (int mt = 0; mt < 4; ++mt)
      #pragma unroll
      for (int nt = 0; nt < 4; ++nt)
        #pragma unroll
        for (int r = 0; r < 4; ++r)
          s[mt][r] += fmaxf(h2[mt][nt][r] + b2v[nt], 0.f) * w3v[nt];

    // reduce across the 16 lanes of each quad (they share rows, differ in col)
    #pragma unroll
    for (int i = 0; i < 16; ++i) {
      float v = s[i >> 2][i & 3];
      v += __shfl_xor(v, 1);
      v += __shfl_xor(v, 2);
      v += __shfl_xor(v, 4);
      v += __shfl_xor(v, 8);
      if (l16 == i) partials[w * 64 + (i >> 2) * 16 + q * 4 + (i & 3)] = v;
    }
    __syncthreads();
    if (tid < 64) {
      float sum = partials[tid] + partials[64 + tid] + partials[128 + tid] + partials[192 + tid];
      fused[tid] += g_lds[tid * NE + e] * (sum + c3[e]);
    }
    __syncthreads();
  }

  if (tid < 64) out[m0 + tid] = fused[tid] + head_b[0];
}

// ---------------------------------------------------------------------------
extern "C" void kernel_launch(void* const* d_in, const int* in_sizes, int n_in,
                              void* d_out, int out_size, void* d_ws, size_t ws_size,
                              hipStream_t stream) {
  const float* x      = (const float*)d_in[0];
  const float* gate_w = (const float*)d_in[1];
  const float* gate_b = (const float*)d_in[2];
  const float* W1     = (const float*)d_in[3];
  const float* b1     = (const float*)d_in[4];
  const float* W2     = (const float*)d_in[5];
  const float* b2     = (const float*)d_in[6];
  const float* W3     = (const float*)d_in[7];
  const float* b3     = (const float*)d_in[8];
  const float* head_w = (const float*)d_in[9];
  const float* head_b = (const float*)d_in[10];
  float* out = (float*)d_out;

  // workspace layout (all 16B-aligned): ~10.5 MB total
  char* ws = (char*)d_ws;
  _Float16* w1p  = (_Float16*)(ws);                  // 4,194,304 B
  _Float16* w2p  = (_Float16*)(ws + 4194304);        // 4,194,304 B
  float*    gts  = (float*)(ws + 8388608);           // 2,097,152 B
  float*    w3h  = (float*)(ws + 10485760);          // 16,384 B
  float*    c3   = (float*)(ws + 10502144);          // 64 B

  hipLaunchKernelGGL(gates_kernel, dim3(B_TOK / 256), dim3(256), 0, stream,
                     x, gate_w, gate_b, gts);
  hipLaunchKernelGGL(pack_w1, dim3(1024), dim3(256), 0, stream, W1, w1p);
  hipLaunchKernelGGL(pack_w2, dim3(1024), dim3(256), 0, stream, W2, w2p);
  hipLaunchKernelGGL(w3h_kernel, dim3(17), dim3(256), 0, stream,
                     W3, b3, head_w, w3h, c3);
  hipLaunchKernelGGL(moe_main, dim3(B_TOK / 64), dim3(256), 0, stream,
                     x, b1, b2, w1p, w2p, gts, w3h, c3, head_b, out);
}

// Round 2
// 412.373 us; speedup vs baseline: 1.1332x; 1.1332x over previous
//
#include <hip/hip_runtime.h>

// Problem constants
#define B_TOK 32768
#define D_IN  256
#define H1D   512
#define H2D   256
#define NE    16
#define NO    64

typedef _Float16 half8 __attribute__((ext_vector_type(8)));
typedef _Float16 half4 __attribute__((ext_vector_type(4)));
typedef float   float4_t __attribute__((ext_vector_type(4)));

// ---------------------------------------------------------------------------
// Pack W1 [E][D][H1] fp32 -> fragment-linear fp16.
// Fragment (e, mtile 0..31, kt 0..7): lane holds W1[e][kt*32+q*8+j][mt*16+l16]
// (serves as A-operand of the transposed L1: A[m=h1col][k=d])
// ---------------------------------------------------------------------------
__global__ void pack_w1(const float* __restrict__ W1, _Float16* __restrict__ w1p) {
  int t = blockIdx.x * 256 + threadIdx.x;        // 16*32*8*64 = 262144 threads
  int lane = t & 63;
  int kt   = (t >> 6) & 7;
  int ntg  = (t >> 9) & 31;
  int e    = t >> 14;
  int n  = ntg * 16 + (lane & 15);
  int kb = kt * 32 + (lane >> 4) * 8;
  half8 v;
  #pragma unroll
  for (int j = 0; j < 8; ++j)
    v[j] = (_Float16)W1[((size_t)(e * D_IN + kb + j)) * H1D + n];
  *(half8*)(w1p + (size_t)t * 8) = v;
}

// Pack W2 [E][H1][H2] fp32 -> fragments: (e, ntile 0..15, ktile 0..15)
__global__ void pack_w2(const float* __restrict__ W2, _Float16* __restrict__ w2p) {
  int t = blockIdx.x * 256 + threadIdx.x;        // 16*16*16*64 = 262144 threads
  int lane = t & 63;
  int ktg  = (t >> 6) & 15;
  int ntg  = (t >> 10) & 15;
  int e    = t >> 14;
  int n  = ntg * 16 + (lane & 15);
  int kb = ktg * 32 + (lane >> 4) * 8;
  half8 v;
  #pragma unroll
  for (int j = 0; j < 8; ++j)
    v[j] = (_Float16)W2[((size_t)(e * H1D + kb + j)) * H2D + n];
  *(half8*)(w2p + (size_t)t * 8) = v;
}

// Pack gate_w [D][E] -> 8 B-fragments (kt 0..7): lane holds gw[kt*32+q*8+j][l16]
__global__ void pack_gate(const float* __restrict__ gw, _Float16* __restrict__ gwp) {
  int t = threadIdx.x;                            // 512 threads, 1 block
  int lane = t & 63;
  int kt   = t >> 6;
  int e  = lane & 15;
  int kb = kt * 32 + (lane >> 4) * 8;
  half8 v;
  #pragma unroll
  for (int j = 0; j < 8; ++j)
    v[j] = (_Float16)gw[(kb + j) * NE + e];
  *(half8*)(gwp + (size_t)t * 8) = v;
}

// w3h[e][h2] = W3[e][h2][:] . head_w ;  c3[e] = b3[e][:] . head_w
__global__ void w3h_kernel(const float* __restrict__ W3, const float* __restrict__ b3,
                           const float* __restrict__ hw, float* __restrict__ w3h,
                           float* __restrict__ c3) {
  int t = blockIdx.x * 256 + threadIdx.x;
  if (t < NE * H2D) {
    int e = t >> 8, h = t & 255;
    float s = 0.f;
    #pragma unroll
    for (int o = 0; o < NO; ++o) s = fmaf(W3[((size_t)(e * H2D + h)) * NO + o], hw[o], s);
    w3h[t] = s;
  } else if (t < NE * H2D + NE) {
    int e = t - NE * H2D;
    float s = 0.f;
    #pragma unroll
    for (int o = 0; o < NO; ++o) s = fmaf(b3[e * NO + o], hw[o], s);
    c3[e] = s;
  }
}

// ---------------------------------------------------------------------------
// Fused main kernel. 512 blocks x 256 threads, 64 tokens/block.
// x tile held in registers as MFMA fragments for the whole kernel (128 VGPR).
// Per expert: L1 (transposed: D[h1col][token], A=W1^T frags global, B=x regs)
//   -> h1 [token][512] in LDS (b64 writes) -> barrier ->
//   L2 (D[token][h2col], A=h1 LDS, B=W2 frags global) + reg-only epilogue
//   -> barrier. Gates computed once at start via MFMA on the same x frags.
// ---------------------------------------------------------------------------
#define H1STR 520   // 512 + 8 halves pad

__global__ __launch_bounds__(256, 2) void moe_main(
    const float* __restrict__ x,
    const float* __restrict__ b1,
    const float* __restrict__ b2,
    const _Float16* __restrict__ w1p,
    const _Float16* __restrict__ w2p,
    const _Float16* __restrict__ gwp,
    const float* __restrict__ gb,
    const float* __restrict__ w3h,
    const float* __restrict__ c3,
    const float* __restrict__ head_b,
    float* __restrict__ out) {
  __shared__ _Float16 h1_lds[64 * H1STR];          // 66.5 KB
  __shared__ float g_lds[NE * 68];                 // [e][token], padded
  __shared__ float fin[4 * 64];

  const int tid  = threadIdx.x;
  const int w    = tid >> 6;
  const int lane = tid & 63;
  const int q    = lane >> 4;
  const int l16  = lane & 15;
  const int m0   = blockIdx.x * 64;
  // token this lane owns in the epilogue reduction
  const int tok_lane = (l16 >> 2) * 16 + q * 4 + (l16 & 3);

  // ---- one-time: load x tile into register fragments xf[token-tile][kt] ----
  half8 xf[4][8];
  #pragma unroll
  for (int nt = 0; nt < 4; ++nt) {
    const float* xr = x + (size_t)(m0 + nt * 16 + l16) * D_IN + q * 8;
    #pragma unroll
    for (int kt = 0; kt < 8; ++kt) {
      float4_t v0 = *(const float4_t*)(xr + kt * 32);
      float4_t v1 = *(const float4_t*)(xr + kt * 32 + 4);
      half8 h;
      h[0] = (_Float16)v0[0]; h[1] = (_Float16)v0[1];
      h[2] = (_Float16)v0[2]; h[3] = (_Float16)v0[3];
      h[4] = (_Float16)v1[0]; h[5] = (_Float16)v1[1];
      h[6] = (_Float16)v1[2]; h[7] = (_Float16)v1[3];
      xf[nt][kt] = h;
    }
  }

  // ---- one-time: gates via MFMA + shuffle softmax; wave w writes tile mt==w ----
  {
    float gbv = gb[l16];
    #pragma unroll
    for (int mt = 0; mt < 4; ++mt) {
      if (mt == w) {   // wave-uniform branch; mt stays a compile-time constant
        float4_t lg = (float4_t){0.f, 0.f, 0.f, 0.f};
        #pragma unroll
        for (int kt = 0; kt < 8; ++kt) {
          half8 bfr = *(const half8*)(gwp + (size_t)kt * 512 + lane * 8);
          lg = __builtin_amdgcn_mfma_f32_16x16x32_f16(xf[mt][kt], bfr, lg, 0, 0, 0);
        }
        #pragma unroll
        for (int r = 0; r < 4; ++r) {
          float v = lg[r] + gbv;                   // logit[token][e=l16]
          float m = v;
          m = fmaxf(m, __shfl_xor(m, 1));
          m = fmaxf(m, __shfl_xor(m, 2));
          m = fmaxf(m, __shfl_xor(m, 4));
          m = fmaxf(m, __shfl_xor(m, 8));
          float p = __expf(v - m);
          float s = p;
          s += __shfl_xor(s, 1);
          s += __shfl_xor(s, 2);
          s += __shfl_xor(s, 4);
          s += __shfl_xor(s, 8);
          g_lds[l16 * 68 + mt * 16 + q * 4 + r] = p / s;
        }
      }
    }
  }

  float yacc = 0.f;

  for (int e = 0; e < NE; ++e) {
    // ================= L1: h1^T tiles, write h1_lds[token][h1col] ===========
    #pragma unroll
    for (int ch = 0; ch < 2; ++ch) {
      float4_t a1[4][4];
      #pragma unroll
      for (int mt = 0; mt < 4; ++mt)
        #pragma unroll
        for (int nt = 0; nt < 4; ++nt)
          a1[mt][nt] = (float4_t){0.f, 0.f, 0.f, 0.f};

      const _Float16* wbase =
          w1p + ((size_t)((e * 32 + ch * 16 + w * 4) * 8)) * 512 + lane * 8;
      #pragma unroll
      for (int kt = 0; kt < 8; ++kt) {
        half8 wc[4];
        #pragma unroll
        for (int mt = 0; mt < 4; ++mt)
          wc[mt] = *(const half8*)(wbase + (size_t)(mt * 8 + kt) * 512);
        #pragma unroll
        for (int mt = 0; mt < 4; ++mt)
          #pragma unroll
          for (int nt = 0; nt < 4; ++nt)
            a1[mt][nt] = __builtin_amdgcn_mfma_f32_16x16x32_f16(
                wc[mt], xf[nt][kt], a1[mt][nt], 0, 0, 0);
      }

      // bias + relu + b64 store (lane holds 4 consecutive h1cols of one token)
      #pragma unroll
      for (int mt = 0; mt < 4; ++mt) {
        int colbase = ch * 256 + (w * 4 + mt) * 16 + q * 4;
        float4_t bb = *(const float4_t*)(b1 + e * H1D + colbase);
        #pragma unroll
        for (int nt = 0; nt < 4; ++nt) {
          half4 hv;
          #pragma unroll
          for (int r = 0; r < 4; ++r)
            hv[r] = (_Float16)fmaxf(a1[mt][nt][r] + bb[r], 0.f);
          *(half4*)(h1_lds + (nt * 16 + l16) * H1STR + colbase) = hv;
        }
      }
    }
    __syncthreads();   // h1 complete & visible

    // ================= L2: h2 = h1 @ W2, wave owns h2cols [w*64, w*64+64) ====
    float4_t h2[4][4];
    #pragma unroll
    for (int mt = 0; mt < 4; ++mt)
      #pragma unroll
      for (int nt = 0; nt < 4; ++nt)
        h2[mt][nt] = (float4_t){0.f, 0.f, 0.f, 0.f};

    const _Float16* w2base =
        w2p + ((size_t)((e * 16 + w * 4) * 16)) * 512 + lane * 8;
    #pragma unroll
    for (int kt = 0; kt < 16; ++kt) {
      half8 w2c[4];
      #pragma unroll
      for (int nt = 0; nt < 4; ++nt)
        w2c[nt] = *(const half8*)(w2base + (size_t)(nt * 16 + kt) * 512);
      half8 hac[4];
      #pragma unroll
      for (int mt = 0; mt < 4; ++mt)
        hac[mt] = *(const half8*)(h1_lds + (mt * 16 + l16) * H1STR + kt * 32 + q * 8);
      #pragma unroll
      for (int mt = 0; mt < 4; ++mt)
        #pragma unroll
        for (int nt = 0; nt < 4; ++nt)
          h2[mt][nt] = __builtin_amdgcn_mfma_f32_16x16x32_f16(
              hac[mt], w2c[nt], h2[mt][nt], 0, 0, 0);
    }

    // ---- register-only epilogue: relu(h2+b2) . w3h, gate, accumulate -------
    float b2v[4], w3v[4];
    #pragma unroll
    for (int nt = 0; nt < 4; ++nt) {
      int n = w * 64 + nt * 16 + l16;
      b2v[nt] = b2[e * H2D + n];
      w3v[nt] = w3h[e * H2D + n];
    }
    float s[4][4];
    #pragma unroll
    for (int mt = 0; mt < 4; ++mt)
      #pragma unroll
      for (int r = 0; r < 4; ++r) s[mt][r] = 0.f;
    #pragma unroll
    for (int mt = 0; mt < 4; ++mt)
      #pragma unroll
      for (int nt = 0; nt < 4; ++nt)
        #pragma unroll
        for (int r = 0; r < 4; ++r)
          s[mt][r] += fmaxf(h2[mt][nt][r] + b2v[nt], 0.f) * w3v[nt];

    float ge = g_lds[e * 68 + tok_lane];
    #pragma unroll
    for (int i = 0; i < 16; ++i) {
      float v = s[i >> 2][i & 3];
      v += __shfl_xor(v, 1);
      v += __shfl_xor(v, 2);
      v += __shfl_xor(v, 4);
      v += __shfl_xor(v, 8);
      if (l16 == i) yacc += ge * v;   // this lane owns token tok_lane
    }
    __syncthreads();   // all h1 reads done before next expert overwrites
  }

  // ---- final cross-wave reduction + gate.c3 + head bias ----
  fin[w * 64 + tok_lane] = yacc;
  __syncthreads();
  if (tid < 64) {
    float sum = fin[tid] + fin[64 + tid] + fin[128 + tid] + fin[192 + tid];
    float gc = 0.f;
    #pragma unroll
    for (int e = 0; e < NE; ++e) gc += g_lds[e * 68 + tid] * c3[e];
    out[m0 + tid] = sum + gc + head_b[0];
  }
}

// ---------------------------------------------------------------------------
extern "C" void kernel_launch(void* const* d_in, const int* in_sizes, int n_in,
                              void* d_out, int out_size, void* d_ws, size_t ws_size,
                              hipStream_t stream) {
  const float* x      = (const float*)d_in[0];
  const float* gate_w = (const float*)d_in[1];
  const float* gate_b = (const float*)d_in[2];
  const float* W1     = (const float*)d_in[3];
  const float* b1     = (const float*)d_in[4];
  const float* W2     = (const float*)d_in[5];
  const float* b2     = (const float*)d_in[6];
  const float* W3     = (const float*)d_in[7];
  const float* b3     = (const float*)d_in[8];
  const float* head_w = (const float*)d_in[9];
  const float* head_b = (const float*)d_in[10];
  float* out = (float*)d_out;

  // workspace layout (16B-aligned)
  char* ws = (char*)d_ws;
  _Float16* w1p = (_Float16*)(ws);                 // 4,194,304 B
  _Float16* w2p = (_Float16*)(ws + 4194304);       // 4,194,304 B
  _Float16* gwp = (_Float16*)(ws + 8388608);       // 8,192 B
  float*    w3h = (float*)(ws + 8396800);          // 16,384 B
  float*    c3  = (float*)(ws + 8413184);          // 64 B

  hipLaunchKernelGGL(pack_w1, dim3(1024), dim3(256), 0, stream, W1, w1p);
  hipLaunchKernelGGL(pack_w2, dim3(1024), dim3(256), 0, stream, W2, w2p);
  hipLaunchKernelGGL(pack_gate, dim3(1), dim3(512), 0, stream, gate_w, gwp);
  hipLaunchKernelGGL(w3h_kernel, dim3(17), dim3(256), 0, stream,
                     W3, b3, head_w, w3h, c3);
  hipLaunchKernelGGL(moe_main, dim3(B_TOK / 64), dim3(256), 0, stream,
                     x, b1, b2, w1p, w2p, gwp, gate_b, w3h, c3, head_b, out);
}